// Round 2
// baseline (404.877 us; speedup 1.0000x reference)
//
#include <hip/hip_runtime.h>
#include <hip/hip_bf16.h>

// Capsule dynamic routing, MFMA bf16 edition.
// x[B=64][J=2048][I=16] fp32, W[N=32][J=2048][D=16][I=16] fp32 -> v[64][32][16] fp32.
//
// Identity: b_k = (sum_{i<k} v_i) . u_hat, so only vsum[B,N,D] is carried; u_hat is
// recomputed each of the 3 passes via mfma_f32_16x16x32_bf16 (K=16 real, upper K
// half nulled by zeroing the B fragment for lanes 32..63).
//
// routing_pass: block = 256 thr = 4 waves; wave w = b-tile [16w,16w+16). Block owns
// ALL 64 b and ALL 32 n for its JC=8 j's -> W and x each read once per pass total.
// Per j: stage W_j (32n x 16d x 16i) as bf16 + x_j (64b x 16i) f32 into LDS
// (double-buffered, 1 barrier/j). Phase 1: per n, MFMA -> U fragment (D layout:
// col=lane&15=b, row=(lane>>4)*4+r=d, verified m89/m91), logit = vs.U via 4 FMA +
// xor16/xor32. Softmax over the 32 in-lane logits (no exchange). Phase 2: per n,
// B-frag = bf16(c_n * x) so acc[n] = mfma(A, c*x, acc[n]) accumulates s directly.
// A-frag layout (m120-verified): A[m=lane&15][k=(lane>>4)*8+t]; m=d rows, k=i.
// W LDS rows padded to 24 bf16 (48B, keeps ds_read_b128 16B-aligned, spreads banks).
//
// sp layout [b][n][chunk][d] (32MB, proven ws budget) so reduce_squash reads are
// fully coalesced (1KB contiguous per wave instruction).

#define J_DIM 2048
#define JC 8
#define NCHUNK (J_DIM / JC)   // 256
#define WPAD 24               // bf16 elems per d-row in LDS
#define XPAD 20               // f32 elems per b-row in LDS

typedef __attribute__((ext_vector_type(8))) short bf16x8;
typedef __attribute__((ext_vector_type(4))) float f32x4;

__device__ inline short f2bf(float f) {
    union { float f; unsigned u; } v; v.f = f;
    unsigned r = v.u + 0x7FFFu + ((v.u >> 16) & 1u);   // RNE
    return (short)(r >> 16);
}

__global__ __launch_bounds__(256, 1)
void routing_pass(const float* __restrict__ x, const float* __restrict__ W,
                  const float* __restrict__ vsum, float* __restrict__ sp) {
    __shared__ short wlds[2][32 * 16 * WPAD];   // 2 x 24KB
    __shared__ float xlds[2][64 * XPAD];        // 2 x 5KB

    const int t    = threadIdx.x;
    const int lane = t & 63;
    const int wv   = t >> 6;          // b-tile 0..3
    const int col  = lane & 15;       // = b_local for B/D, = d-row for A
    const int g    = lane >> 4;       // 0..3
    const int b    = wv * 16 + col;
    const int chunk = blockIdx.x;
    const int jbase = chunk * JC;

    // staging maps (256 threads)
    const int sn = t >> 3;            // 0..31 (n)
    const int sd = (t & 7) * 2;       // even d; thread does rows sd, sd+1
    const int xb = t >> 2;            // 0..63 (b)
    const int xi = (t & 3) * 4;       // i quad

    auto stage = [&](int j, int jb) {
        // W[sn, j, sd..sd+1, 0..15] : 32 consecutive floats
        const float* wsrc = W + ((size_t)sn * J_DIM + j) * 256 + sd * 16;
        float4 q[8];
#pragma unroll
        for (int k = 0; k < 8; ++k) q[k] = ((const float4*)wsrc)[k];
        short tmp[32];
#pragma unroll
        for (int k = 0; k < 8; ++k) {
            tmp[4 * k + 0] = f2bf(q[k].x); tmp[4 * k + 1] = f2bf(q[k].y);
            tmp[4 * k + 2] = f2bf(q[k].z); tmp[4 * k + 3] = f2bf(q[k].w);
        }
        short* wr = &wlds[jb][(sn * 16 + sd) * WPAD];
        *(bf16x8*)(wr)            = *(bf16x8*)&tmp[0];
        *(bf16x8*)(wr + 8)        = *(bf16x8*)&tmp[8];
        *(bf16x8*)(wr + WPAD)     = *(bf16x8*)&tmp[16];
        *(bf16x8*)(wr + WPAD + 8) = *(bf16x8*)&tmp[24];
        // x[xb, j, xi..xi+3]
        float4 xq = *(const float4*)(x + (size_t)xb * (J_DIM * 16) + (size_t)j * 16 + xi);
        *(float4*)&xlds[jb][xb * XPAD + xi] = xq;
    };

    f32x4 acc[32];
#pragma unroll
    for (int n = 0; n < 32; ++n) acc[n] = (f32x4){0.f, 0.f, 0.f, 0.f};

    int jb = 0;
    stage(jbase, 0);

    for (int js = 0; js < JC; ++js) {
        __syncthreads();                       // staged buffer jb is ready
        if (js + 1 < JC) stage(jbase + js + 1, jb ^ 1);

        // B fragment: x[b, j, k] for k = (g&1)*8..+7 ; zero for k>=16 (g>=2)
        float x8[8];
        const float* xrow = &xlds[jb][b * XPAD + (g & 1) * 8];
#pragma unroll
        for (int k = 0; k < 8; ++k) x8[k] = (lane < 32) ? xrow[k] : 0.f;
        bf16x8 xbf;
#pragma unroll
        for (int k = 0; k < 8; ++k) xbf[k] = f2bf(x8[k]);

        // ---- phase 1: logits for all 32 n ----
        float logit[32];
#pragma unroll
        for (int n = 0; n < 32; ++n) {
            bf16x8 af = *(const bf16x8*)&wlds[jb][(n * 16 + col) * WPAD + (g & 1) * 8];
            f32x4 u = __builtin_amdgcn_mfma_f32_16x16x32_bf16(
                af, xbf, (f32x4){0.f, 0.f, 0.f, 0.f}, 0, 0, 0);
            float4 vv = *(const float4*)(vsum + ((size_t)b * 32 + n) * 16 + g * 4);
            float lp = vv.x * u[0] + vv.y * u[1] + vv.z * u[2] + vv.w * u[3];
            lp += __shfl_xor(lp, 16);
            lp += __shfl_xor(lp, 32);
            logit[n] = lp;
        }

        // ---- softmax over n, fully in-lane ----
        float mx = logit[0];
#pragma unroll
        for (int n = 1; n < 32; ++n) mx = fmaxf(mx, logit[n]);
        float Z = 0.f;
#pragma unroll
        for (int n = 0; n < 32; ++n) { logit[n] = __expf(logit[n] - mx); Z += logit[n]; }
        float rz = __builtin_amdgcn_rcpf(Z);

        // ---- phase 2: acc[n] += c_n * u_n via c-scaled B fragment ----
#pragma unroll
        for (int n = 0; n < 32; ++n) {
            float c = logit[n] * rz;
            bf16x8 bs;
#pragma unroll
            for (int k = 0; k < 8; ++k) bs[k] = f2bf(x8[k] * c);
            bf16x8 af = *(const bf16x8*)&wlds[jb][(n * 16 + col) * WPAD + (g & 1) * 8];
            acc[n] = __builtin_amdgcn_mfma_f32_16x16x32_bf16(af, bs, acc[n], 0, 0, 0);
        }
        jb ^= 1;
    }

    // epilogue: sp[b][n][chunk][d], lane writes d = g*4..g*4+3
#pragma unroll
    for (int n = 0; n < 32; ++n) {
        float* o = sp + (((size_t)b * 32 + n) * NCHUNK + chunk) * 16 + g * 4;
        *(float4*)o = make_float4(acc[n][0], acc[n][1], acc[n][2], acc[n][3]);
    }
}

// block = 256 thr = 4 waves, one (b,n) per wave; fully coalesced partial fold.
__global__ __launch_bounds__(256)
void reduce_squash(const float* __restrict__ sp, float* __restrict__ vsum,
                   float* __restrict__ out, int is_last) {
    const int t    = threadIdx.x;
    const int lane = t & 63;
    const int wv   = t >> 6;
    const int bn   = blockIdx.x * 4 + wv;     // 0..2047
    const int dq   = lane & 3;                // d quad
    const int c0   = lane >> 2;               // 0..15

    float ax = 0.f, ay = 0.f, az = 0.f, aw = 0.f;
    const float* base = sp + (size_t)bn * NCHUNK * 16 + dq * 4;
#pragma unroll
    for (int m = 0; m < 16; ++m) {
        float4 v = *(const float4*)(base + (size_t)(c0 + 16 * m) * 16);
        ax += v.x; ay += v.y; az += v.z; aw += v.w;
    }
    // fold chunks across lanes sharing dq
#pragma unroll
    for (int mk = 4; mk <= 32; mk <<= 1) {
        ax += __shfl_xor(ax, mk); ay += __shfl_xor(ay, mk);
        az += __shfl_xor(az, mk); aw += __shfl_xor(aw, mk);
    }
    // squash
    float tt = ax * ax + ay * ay + az * az + aw * aw;
    tt += __shfl_xor(tt, 1);
    tt += __shfl_xor(tt, 2);
    float s2 = tt + 1e-7f;
    float scale = sqrtf(s2) / (1.0f + s2);

    if (lane < 4) {
        float4 v = make_float4(ax * scale, ay * scale, az * scale, aw * scale);
        if (is_last) {
            *(float4*)(out + (size_t)bn * 16 + dq * 4) = v;
        } else {
            float* p = vsum + (size_t)bn * 16 + dq * 4;
            float4 old = *(const float4*)p;
            *(float4*)p = make_float4(old.x + v.x, old.y + v.y, old.z + v.z, old.w + v.w);
        }
    }
}

extern "C" void kernel_launch(void* const* d_in, const int* in_sizes, int n_in,
                              void* d_out, int out_size, void* d_ws, size_t ws_size,
                              hipStream_t stream) {
    const float* x = (const float*)d_in[0];   // [64,2048,16]
    const float* W = (const float*)d_in[1];   // [32,2048,16,16]
    float* out = (float*)d_out;               // [64,32,16]

    float* sp   = (float*)d_ws;               // [64][32][256][16] = 32 MB
    float* vsum = sp + (size_t)64 * 32 * NCHUNK * 16;  // [64][32][16] = 128 KB

    hipMemsetAsync(vsum, 0, 64 * 32 * 16 * sizeof(float), stream);

    for (int pass = 0; pass < 3; ++pass) {
        routing_pass<<<dim3(NCHUNK), dim3(256), 0, stream>>>(x, W, vsum, sp);
        reduce_squash<<<dim3(2048 / 4), dim3(256), 0, stream>>>(sp, vsum, out, pass == 2);
    }
}

// Round 3
// 295.200 us; speedup vs baseline: 1.3715x; 1.3715x over previous
//
#include <hip/hip_runtime.h>
#include <hip/hip_bf16.h>

// Capsule dynamic routing, round 3: decoupled low-state kernels.
// x[64][2048][16] f32, W[32][2048][16][16] f32 -> v[64][32][16] f32.
//
// Identity: b_k = (sum_{i<k} v_i) . u_hat  -> carry only vsum[64][32][16].
// Per pass: logits_k (MFMA u_hat + vsum dot -> L[j][n][b]), softmax_k (in-place
// over n), wsum_k (c folded into B operand, K=32 = 2 j's per MFMA, ONE f32x4
// accumulator per wave), reduce_k (fold 32 chunk partials + squash).
// Pass 0: logits == 0 -> softmax uniform 1/32 -> wsum_k uniform flag, skip A/SM.
//
// Prologue converts W,x to bf16 once (Wbf 32MB, xbf 4MB in ws) so hot loops do
// zero f32->bf16 conversion of W and read half the bytes.
//
// MFMA layouts (m89/m91/m120-verified): C/D col=lane&15, row=(lane>>4)*4+reg.
// A[m=lane&15][k=(lane>>4)*8+t]. wsum_k packs k=0..15 -> j0, k=16..31 -> j0+1:
// af load = Wbf[n][j0+(g>>1)][col][(g&1)*8..+7] -- wave reads 1KB contiguous.

#define J_DIM 2048

typedef __attribute__((ext_vector_type(8))) short bf16x8;
typedef __attribute__((ext_vector_type(4))) float f32x4;

__device__ inline short f2bf(float f) {
    union { float f; unsigned u; } v; v.f = f;
    unsigned r = v.u + 0x7FFFu + ((v.u >> 16) & 1u);   // RNE
    return (short)(r >> 16);
}

// each thread converts 8 floats -> 8 bf16
__global__ __launch_bounds__(256)
void cvt_bf16(const float* __restrict__ src, short* __restrict__ dst, int n8) {
    int id = blockIdx.x * 256 + threadIdx.x;
    if (id >= n8) return;
    const float4* s = (const float4*)(src + (size_t)id * 8);
    float4 a = s[0], b = s[1];
    short t[8] = { f2bf(a.x), f2bf(a.y), f2bf(a.z), f2bf(a.w),
                   f2bf(b.x), f2bf(b.y), f2bf(b.z), f2bf(b.w) };
    *(bf16x8*)(dst + (size_t)id * 8) = *(bf16x8*)t;
}

// L[j][n][b] = vsum[b,n,:] . u_hat[b,n,j,:]
// grid(64 jchunks, 8 ngroups) x 256thr; wave w -> n = y*4+w, 32 j's, 4 b-tiles.
__global__ __launch_bounds__(256)
void logits_k(const short* __restrict__ Wbf, const short* __restrict__ xbf,
              const float* __restrict__ vsum, float* __restrict__ L) {
    const int t = threadIdx.x, lane = t & 63, w = t >> 6;
    const int col = lane & 15, g = lane >> 4;
    const int n = blockIdx.y * 4 + w;
    const int j0 = blockIdx.x * 32;

    float4 vv[4];
#pragma unroll
    for (int bt = 0; bt < 4; ++bt)
        vv[bt] = *(const float4*)(vsum + ((size_t)(bt * 16 + col) * 32 + n) * 16 + g * 4);

    const bool klo = (lane < 32);
    for (int js = 0; js < 32; ++js) {
        int j = j0 + js;
        // A-frag: m=col=d, k=g*8+t = i (k>=16 garbage, nulled via B) ; 16B load
        bf16x8 af = *(const bf16x8*)(Wbf + ((size_t)n * J_DIM + j) * 256 + col * 16 + g * 8);
        float l4[4];
#pragma unroll
        for (int bt = 0; bt < 4; ++bt) {
            bf16x8 xb = *(const bf16x8*)(xbf + ((size_t)(bt * 16 + col) * J_DIM + j) * 16 + (g & 1) * 8);
            if (!klo) xb = (bf16x8){0, 0, 0, 0, 0, 0, 0, 0};
            f32x4 u = __builtin_amdgcn_mfma_f32_16x16x32_bf16(
                af, xb, (f32x4){0.f, 0.f, 0.f, 0.f}, 0, 0, 0);
            float lp = vv[bt].x * u[0] + vv[bt].y * u[1] + vv[bt].z * u[2] + vv[bt].w * u[3];
            lp += __shfl_xor(lp, 16);
            lp += __shfl_xor(lp, 32);
            l4[bt] = lp;
        }
        float myl = (g == 0) ? l4[0] : (g == 1) ? l4[1] : (g == 2) ? l4[2] : l4[3];
        L[((size_t)j * 32 + n) * 64 + g * 16 + col] = myl;   // wave: 256B contiguous
    }
}

// in-place softmax over n for each (b,j); wave=j, lane=b, coalesced 256B rows.
__global__ __launch_bounds__(256)
void softmax_k(float* __restrict__ L) {
    const int t = threadIdx.x, lane = t & 63, w = t >> 6;
    const int j = blockIdx.x * 4 + w;
    float* row = L + (size_t)j * 32 * 64 + lane;
    float l[32];
#pragma unroll
    for (int n = 0; n < 32; ++n) l[n] = row[n * 64];
    float mx = l[0];
#pragma unroll
    for (int n = 1; n < 32; ++n) mx = fmaxf(mx, l[n]);
    float Z = 0.f;
#pragma unroll
    for (int n = 0; n < 32; ++n) { l[n] = __expf(l[n] - mx); Z += l[n]; }
    float rz = __builtin_amdgcn_rcpf(Z);
#pragma unroll
    for (int n = 0; n < 32; ++n) row[n * 64] = l[n] * rz;
}

// sp[chunk][n][b][d] += over 64 j's: c[b,n,j] * u_hat[b,n,j,d]
// grid(32 chunks, 8 ngroups, 4 btiles) x 256thr; K=32 = 2 j per MFMA; acc = 1 f32x4.
__global__ __launch_bounds__(256)
void wsum_k(const short* __restrict__ Wbf, const float* __restrict__ x,
            const float* __restrict__ C, float* __restrict__ sp, int uniform) {
    const int t = threadIdx.x, lane = t & 63, w = t >> 6;
    const int col = lane & 15, g = lane >> 4;
    const int n = blockIdx.y * 4 + w;
    const int bt = blockIdx.z;
    const int b = bt * 16 + col;
    const int chunk = blockIdx.x;

    f32x4 acc = (f32x4){0.f, 0.f, 0.f, 0.f};
    for (int jp = 0; jp < 32; ++jp) {
        const int jq = chunk * 64 + jp * 2 + (g >> 1);
        // A[m=col=d][k=g*8+t] = W[n, jq, col, (g&1)*8+t]; wave = 1KB contiguous
        bf16x8 af = *(const bf16x8*)(Wbf + ((size_t)n * J_DIM + jq) * 256 + col * 16 + (g & 1) * 8);
        const float4* xp = (const float4*)(x + ((size_t)b * J_DIM + jq) * 16 + (g & 1) * 8);
        float4 x0 = xp[0], x1 = xp[1];
        float cc = uniform ? 0.03125f : C[((size_t)jq * 32 + n) * 64 + b];
        short bs[8] = { f2bf(cc * x0.x), f2bf(cc * x0.y), f2bf(cc * x0.z), f2bf(cc * x0.w),
                        f2bf(cc * x1.x), f2bf(cc * x1.y), f2bf(cc * x1.z), f2bf(cc * x1.w) };
        acc = __builtin_amdgcn_mfma_f32_16x16x32_bf16(af, *(bf16x8*)bs, acc, 0, 0, 0);
    }
    float* o = sp + (((size_t)chunk * 32 + n) * 64 + b) * 16 + g * 4;
    *(float4*)o = make_float4(acc[0], acc[1], acc[2], acc[3]);   // wave: 1KB contiguous
}

// fold 32 chunk partials, squash, update vsum / write out. wave per (n,b).
__global__ __launch_bounds__(256)
void reduce_k(const float* __restrict__ sp, float* __restrict__ vsum,
              float* __restrict__ out, int is_last) {
    const int t = threadIdx.x, lane = t & 63, w = t >> 6;
    const int q = blockIdx.x * 4 + w;       // 0..2047
    const int n = q >> 6, b = q & 63;
    const int d4 = lane & 3, ch = lane >> 2;   // ch 0..15

    float4 a = make_float4(0.f, 0.f, 0.f, 0.f);
#pragma unroll
    for (int m = 0; m < 2; ++m) {
        float4 v = *(const float4*)(sp + (((size_t)(ch + 16 * m) * 32 + n) * 64 + b) * 16 + d4 * 4);
        a.x += v.x; a.y += v.y; a.z += v.z; a.w += v.w;
    }
#pragma unroll
    for (int mk = 4; mk <= 32; mk <<= 1) {
        a.x += __shfl_xor(a.x, mk); a.y += __shfl_xor(a.y, mk);
        a.z += __shfl_xor(a.z, mk); a.w += __shfl_xor(a.w, mk);
    }
    float tt = a.x * a.x + a.y * a.y + a.z * a.z + a.w * a.w;
    tt += __shfl_xor(tt, 1);
    tt += __shfl_xor(tt, 2);
    float s2 = tt + 1e-7f;
    float scale = sqrtf(s2) / (1.0f + s2);

    if (lane < 4) {
        float4 v = make_float4(a.x * scale, a.y * scale, a.z * scale, a.w * scale);
        float* p = (is_last ? out : vsum) + ((size_t)b * 32 + n) * 16 + d4 * 4;
        if (is_last) {
            *(float4*)p = v;
        } else {
            float4 o = *(const float4*)p;
            *(float4*)p = make_float4(o.x + v.x, o.y + v.y, o.z + v.z, o.w + v.w);
        }
    }
}

extern "C" void kernel_launch(void* const* d_in, const int* in_sizes, int n_in,
                              void* d_out, int out_size, void* d_ws, size_t ws_size,
                              hipStream_t stream) {
    const float* x = (const float*)d_in[0];   // [64,2048,16]
    const float* W = (const float*)d_in[1];   // [32,2048,16,16]
    float* out = (float*)d_out;               // [64,32,16]

    char* wsb = (char*)d_ws;
    short* Wbf  = (short*)(wsb);                         // 32 MB (+2KB slack for g>=2 tail reads)
    short* xbf  = (short*)(wsb + 33556480);              // 4 MB
    float* L    = (float*)(wsb + 37750784);              // 16 MB  [j][n][b]
    float* sp   = (float*)(wsb + 54528000);              // 4 MB   [chunk][n][b][d]
    float* vsum = (float*)(wsb + 58722304);              // 128 KB [b][n][d]

    cvt_bf16<<<8192, 256, 0, stream>>>(W, Wbf, 2097152);
    cvt_bf16<<<1024, 256, 0, stream>>>(x, xbf, 262144);
    hipMemsetAsync(vsum, 0, 64 * 32 * 16 * sizeof(float), stream);

    // pass 0: logits == 0 -> uniform c
    wsum_k<<<dim3(32, 8, 4), 256, 0, stream>>>(Wbf, x, L, sp, 1);
    reduce_k<<<512, 256, 0, stream>>>(sp, vsum, out, 0);
    // pass 1
    logits_k<<<dim3(64, 8), 256, 0, stream>>>(Wbf, xbf, vsum, L);
    softmax_k<<<512, 256, 0, stream>>>(L);
    wsum_k<<<dim3(32, 8, 4), 256, 0, stream>>>(Wbf, x, L, sp, 0);
    reduce_k<<<512, 256, 0, stream>>>(sp, vsum, out, 0);
    // pass 2
    logits_k<<<dim3(64, 8), 256, 0, stream>>>(Wbf, xbf, vsum, L);
    softmax_k<<<512, 256, 0, stream>>>(L);
    wsum_k<<<dim3(32, 8, 4), 256, 0, stream>>>(Wbf, x, L, sp, 0);
    reduce_k<<<512, 256, 0, stream>>>(sp, vsum, out, 1);
}